// Round 1
// baseline (471.583 us; speedup 1.0000x reference)
//
#include <hip/hip_runtime.h>
#include <stdint.h>

// ---------------------------------------------------------------------------
// StageBranchRunnerN2: LN -> proj MLP -> router MLP -> top2 softmax -> MoE FFN
// Round 0: f32 router chain (top-2 selection is tie-sensitive; bf16 noise
// flips rank2/rank3 on ~1% tokens -> absmax blowup), bf16 MFMA expert path
// (dense, gate folded into GEMM2's A operand as row scaling).
// ---------------------------------------------------------------------------

typedef unsigned short u16;
using bf16x8 = __attribute__((ext_vector_type(8))) short;
using f32x4  = __attribute__((ext_vector_type(4))) float;

#define NTOK 8192

__device__ __forceinline__ float gelu_tanh(float x) {
  // jax.nn.gelu approximate=True (tanh form)
  float x3 = x * x * x;
  float t = tanhf(0.7978845608028654f * (x + 0.044715f * x3));
  return 0.5f * x * (1.0f + t);
}

__device__ __forceinline__ u16 f2bf(float f) {
  uint32_t u = __float_as_uint(f);
  u = u + 0x7fffu + ((u >> 16) & 1u);   // RNE
  return (u16)(u >> 16);
}

// ---------------------------------------------------------------------------
// Weight prep: e_w1 (8,1024,256) -> w1t[n=e*256+h][k] (2048x1024 bf16, B^T)
//              e_w2 (8,256,1024) -> w2t[d][q=e*256+h]  (1024x2048 bf16, B^T)
// ---------------------------------------------------------------------------
__global__ __launch_bounds__(256) void prep_kernel(const float* __restrict__ ew1,
                                                   const float* __restrict__ ew2,
                                                   u16* __restrict__ w1t,
                                                   u16* __restrict__ w2t) {
  int idx = blockIdx.x * 256 + threadIdx.x;
  if (idx < (1 << 21)) {
    int k = idx & 1023, n = idx >> 10;
    int e = n >> 8, h = n & 255;
    w1t[idx] = f2bf(ew1[(e << 18) + (k << 8) + h]);
  } else {
    int j = idx - (1 << 21);
    int d = j >> 11, q = j & 2047;
    w2t[j] = f2bf(ew2[q * 1024 + d]);
  }
}

// ---------------------------------------------------------------------------
// LayerNorm (two-pass, f32) -> ri[:,0:1024] f32 + hnb bf16; also rule logits.
// One block per token.
// ---------------------------------------------------------------------------
__global__ __launch_bounds__(256) void ln_kernel(const float* __restrict__ hidden,
    const float* __restrict__ ln_g, const float* __restrict__ ln_b,
    const float* __restrict__ feat, const float* __restrict__ rr_w,
    const float* __restrict__ rr_b,
    float* __restrict__ ri, u16* __restrict__ hnb, float* __restrict__ rule) {
  int t = blockIdx.x;
  int tid = threadIdx.x;
  float4 v = ((const float4*)(hidden + (size_t)t * 1024))[tid];
  float s = v.x + v.y + v.z + v.w;
#pragma unroll
  for (int o = 32; o > 0; o >>= 1) s += __shfl_down(s, o);
  __shared__ float red[4];
  __shared__ float stats[2];
  int wid = tid >> 6, lane = tid & 63;
  if (lane == 0) red[wid] = s;
  __syncthreads();
  if (tid == 0) stats[0] = (red[0] + red[1] + red[2] + red[3]) * (1.0f / 1024.0f);
  __syncthreads();
  float mu = stats[0];
  float dx = v.x - mu, dy = v.y - mu, dz = v.z - mu, dw = v.w - mu;
  float q = dx * dx + dy * dy + dz * dz + dw * dw;
#pragma unroll
  for (int o = 32; o > 0; o >>= 1) q += __shfl_down(q, o);
  if (lane == 0) red[wid] = q;
  __syncthreads();
  if (tid == 0) {
    float var = (red[0] + red[1] + red[2] + red[3]) * (1.0f / 1024.0f) + 1e-5f;
    float r = rsqrtf(var);
    r = r * (1.5f - 0.5f * var * r * r);   // Newton refine
    stats[1] = r;
  }
  __syncthreads();
  float r = stats[1];
  float4 g = ((const float4*)ln_g)[tid];
  float4 b = ((const float4*)ln_b)[tid];
  float4 o;
  o.x = dx * r * g.x + b.x;
  o.y = dy * r * g.y + b.y;
  o.z = dz * r * g.z + b.z;
  o.w = dw * r * g.w + b.w;
  ((float4*)(ri + (size_t)t * 1280))[tid] = o;
  ushort4 ub;
  ub.x = f2bf(o.x); ub.y = f2bf(o.y); ub.z = f2bf(o.z); ub.w = f2bf(o.w);
  ((ushort4*)(hnb + (size_t)t * 1024))[tid] = ub;
  if (tid < 8) {
    float acc = rr_b[tid];
#pragma unroll
    for (int f = 0; f < 16; f++) acc += feat[t * 16 + f] * rr_w[f * 8 + tid];
    rule[t * 8 + tid] = acc;   // TEMP = 1
  }
}

// ---------------------------------------------------------------------------
// f32 SGEMM: C[M x 256] = A[M x K] @ B[K x 256] + bias (optional gelu).
// BM=64, BN=64, BK=16, 256 threads, 4x4 per thread. ldb hardcoded 256.
// ---------------------------------------------------------------------------
__global__ __launch_bounds__(256) void sgemm_kernel(const float* __restrict__ A, int lda,
    const float* __restrict__ B, const float* __restrict__ bias,
    float* __restrict__ C, int ldc, int K, int do_gelu) {
  __shared__ float As[16][68];
  __shared__ float Bs[16][72];
  int tid = threadIdx.x;
  int trow = tid >> 4, tcol = tid & 15;
  int row0 = blockIdx.y * 64, col0 = blockIdx.x * 64;
  int ar = tid >> 2, akc = tid & 3;
  int bk = tid >> 4, bn = tid & 15;
  float acc[4][4] = {};
  const float* Ap = A + (size_t)(row0 + ar) * lda + akc * 4;
  const float* Bp = B + (size_t)bk * 256 + col0 + bn * 4;
  for (int k0 = 0; k0 < K; k0 += 16) {
    float4 va = *((const float4*)(Ap + k0));
    float4 vb = *((const float4*)(Bp + (size_t)k0 * 256));
    __syncthreads();
    As[akc * 4 + 0][ar] = va.x;
    As[akc * 4 + 1][ar] = va.y;
    As[akc * 4 + 2][ar] = va.z;
    As[akc * 4 + 3][ar] = va.w;
    *((float4*)&Bs[bk][bn * 4]) = vb;
    __syncthreads();
#pragma unroll
    for (int k = 0; k < 16; k++) {
      float4 a4 = *((const float4*)&As[k][trow * 4]);
      float4 b4 = *((const float4*)&Bs[k][tcol * 4]);
      float av[4] = {a4.x, a4.y, a4.z, a4.w};
      float bv[4] = {b4.x, b4.y, b4.z, b4.w};
#pragma unroll
      for (int i = 0; i < 4; i++)
#pragma unroll
        for (int j = 0; j < 4; j++) acc[i][j] += av[i] * bv[j];
    }
  }
  int rg = row0 + trow * 4, cg = col0 + tcol * 4;
  float4 biv = *((const float4*)(bias + cg));
#pragma unroll
  for (int i = 0; i < 4; i++) {
    float4 ov;
    ov.x = acc[i][0] + biv.x;
    ov.y = acc[i][1] + biv.y;
    ov.z = acc[i][2] + biv.z;
    ov.w = acc[i][3] + biv.w;
    if (do_gelu) {
      ov.x = gelu_tanh(ov.x); ov.y = gelu_tanh(ov.y);
      ov.z = gelu_tanh(ov.z); ov.w = gelu_tanh(ov.w);
    }
    *((float4*)(C + (size_t)(rg + i) * ldc + cg)) = ov;
  }
}

// ---------------------------------------------------------------------------
// Router head: logits = r1 @ r_w2 + r_b2; top-2 masked softmax; outputs
// gate_weights, scaled_logits, group_weights. 32 tokens/block, 8 thr/token.
// ---------------------------------------------------------------------------
__global__ __launch_bounds__(256) void gate_kernel(const float* __restrict__ r1,
    const float* __restrict__ r_w2, const float* __restrict__ r_b2,
    float* __restrict__ gates, float* __restrict__ slog, float* __restrict__ gw) {
  __shared__ float w2s[2048];
  __shared__ float r1s[32][260];
  __shared__ float lg[32][8];
  int tid = threadIdx.x;
  int t0 = blockIdx.x * 32;
  for (int i = tid; i < 2048; i += 256) w2s[i] = r_w2[i];
  for (int i = tid; i < 32 * 256; i += 256) {
    int tt = i >> 8, k = i & 255;
    r1s[tt][k] = r1[(size_t)(t0 + tt) * 256 + k];
  }
  __syncthreads();
  int tl = tid >> 3, e = tid & 7;
  float acc = r_b2[e];
  for (int k = 0; k < 256; k++) acc += r1s[tl][k] * w2s[k * 8 + e];
  lg[tl][e] = acc;
  __syncthreads();
  if (tid < 32) {
    int t = t0 + tid;
    float l[8];
#pragma unroll
    for (int i = 0; i < 8; i++) l[i] = lg[tid][i];
    float m1 = -1e30f, m2 = -1e30f;
#pragma unroll
    for (int i = 0; i < 8; i++) {
      float v = l[i];
      if (v > m1) { m2 = m1; m1 = v; }
      else if (v > m2) m2 = v;
    }
    float w[8];
    float se = 0.0f;
#pragma unroll
    for (int i = 0; i < 8; i++) {
      float ex = (l[i] >= m2) ? expf(l[i] - m1) : 0.0f;
      w[i] = ex;
      se += ex;
    }
    float inv = 1.0f / se;
#pragma unroll
    for (int i = 0; i < 8; i++) {
      gates[(size_t)t * 8 + i] = w[i] * inv;
      slog[(size_t)t * 8 + i] = l[i];
    }
#pragma unroll
    for (int gi = 0; gi < 4; gi++)
      gw[(size_t)t * 4 + gi] = (w[2 * gi] + w[2 * gi + 1]) * inv;
  }
}

// ---------------------------------------------------------------------------
// bf16 MFMA GEMM, C = A(MxK) @ Bt(NxK)^T, 128x128 tile, 16x16x32 MFMA.
// MODE 0: +e_b1, gelu, *gate -> bf16 A' (expert GEMM1, N=2048)
// MODE 1: +sum_e g*e_b2, write stage_out & next_hidden (expert GEMM2, N=1024)
// ---------------------------------------------------------------------------
template <int MODE>
__global__ __launch_bounds__(256) void mfma_gemm(const u16* __restrict__ A,
    const u16* __restrict__ Bt, int N, int K,
    const float* __restrict__ bias, const float* __restrict__ gates,
    u16* __restrict__ outb, const float* __restrict__ hidden,
    const float* __restrict__ alpha_p, float* __restrict__ stage,
    float* __restrict__ next) {
  __shared__ u16 As[128 * 32];
  __shared__ u16 Bs[128 * 32];
  __shared__ float gs[128 * 8];
  __shared__ float b2s[8 * 128];
  int tid = threadIdx.x;
  int row0 = blockIdx.y * 128, col0 = blockIdx.x * 128;
  int wave = tid >> 6, lane = tid & 63;
  int wr = (wave >> 1) * 64, wc = (wave & 1) * 64;
  int l16 = lane & 15, qd = lane >> 4;
  f32x4 acc[4][4];
#pragma unroll
  for (int i = 0; i < 4; i++)
#pragma unroll
    for (int j = 0; j < 4; j++) acc[i][j] = 0.0f;

  int r0 = tid >> 2, kc = tid & 3;   // staging chunk: row r0, 16B chunk kc
  const u16* Ap0 = A + (size_t)(row0 + r0) * K + kc * 8;
  const u16* Ap1 = A + (size_t)(row0 + 64 + r0) * K + kc * 8;
  const u16* Bp0 = Bt + (size_t)(col0 + r0) * K + kc * 8;
  const u16* Bp1 = Bt + (size_t)(col0 + 64 + r0) * K + kc * 8;
  u16* Asw0 = As + r0 * 32 + kc * 8;
  u16* Asw1 = As + (64 + r0) * 32 + kc * 8;
  u16* Bsw0 = Bs + r0 * 32 + kc * 8;
  u16* Bsw1 = Bs + (64 + r0) * 32 + kc * 8;

  for (int k0 = 0; k0 < K; k0 += 32) {
    uint4 a0 = *((const uint4*)(Ap0 + k0));
    uint4 a1 = *((const uint4*)(Ap1 + k0));
    uint4 b0 = *((const uint4*)(Bp0 + k0));
    uint4 b1 = *((const uint4*)(Bp1 + k0));
    __syncthreads();
    *((uint4*)Asw0) = a0;
    *((uint4*)Asw1) = a1;
    *((uint4*)Bsw0) = b0;
    *((uint4*)Bsw1) = b1;
    __syncthreads();
    bf16x8 af[4], bfr[4];
#pragma unroll
    for (int i = 0; i < 4; i++) {
      af[i]  = *((const bf16x8*)(As + (wr + i * 16 + l16) * 32 + qd * 8));
      bfr[i] = *((const bf16x8*)(Bs + (wc + i * 16 + l16) * 32 + qd * 8));
    }
#pragma unroll
    for (int i = 0; i < 4; i++)
#pragma unroll
      for (int j = 0; j < 4; j++)
        acc[i][j] = __builtin_amdgcn_mfma_f32_16x16x32_bf16(af[i], bfr[j], acc[i][j], 0, 0, 0);
  }

  for (int i = tid; i < 1024; i += 256)
    gs[i] = gates[(size_t)(row0 + (i >> 3)) * 8 + (i & 7)];
  if (MODE == 1) {
    for (int i = tid; i < 1024; i += 256)
      b2s[i] = bias[(size_t)(i >> 7) * 1024 + col0 + (i & 127)];
  }
  __syncthreads();

  if (MODE == 0) {
#pragma unroll
    for (int i = 0; i < 4; i++) {
#pragma unroll
      for (int j = 0; j < 4; j++) {
        int cl = wc + j * 16 + l16;
        int col = col0 + cl;
        float bcol = bias[col];
        int e = col >> 8;
#pragma unroll
        for (int rr = 0; rr < 4; rr++) {
          int rl = wr + i * 16 + qd * 4 + rr;
          int row = row0 + rl;
          float v = acc[i][j][rr] + bcol;
          v = gelu_tanh(v) * gs[rl * 8 + e];
          outb[(size_t)row * N + col] = f2bf(v);
        }
      }
    }
  } else {
    float al = alpha_p[0];
#pragma unroll
    for (int i = 0; i < 4; i++) {
#pragma unroll
      for (int j = 0; j < 4; j++) {
        int cl = wc + j * 16 + l16;
        int col = col0 + cl;
#pragma unroll
        for (int rr = 0; rr < 4; rr++) {
          int rl = wr + i * 16 + qd * 4 + rr;
          int row = row0 + rl;
          float sb = 0.0f;
#pragma unroll
          for (int e = 0; e < 8; e++) sb += gs[rl * 8 + e] * b2s[e * 128 + cl];
          float v = acc[i][j][rr] + sb;
          size_t o = (size_t)row * N + col;
          stage[o] = v;
          next[o] = hidden[o] + al * v;
        }
      }
    }
  }
}

// ---------------------------------------------------------------------------
extern "C" void kernel_launch(void* const* d_in, const int* in_sizes, int n_in,
                              void* d_out, int out_size, void* d_ws, size_t ws_size,
                              hipStream_t stream) {
  const float* hidden   = (const float*)d_in[0];
  const float* feat     = (const float*)d_in[1];
  const float* feat_bank= (const float*)d_in[2];
  // d_in[3] item_seq_len: unused by reference
  const float* ln_g = (const float*)d_in[4];
  const float* ln_b = (const float*)d_in[5];
  const float* fp_w1 = (const float*)d_in[6];
  const float* fp_b1 = (const float*)d_in[7];
  const float* fp_w2 = (const float*)d_in[8];
  const float* fp_b2 = (const float*)d_in[9];
  const float* r_w1 = (const float*)d_in[10];
  const float* r_b1 = (const float*)d_in[11];
  const float* r_w2 = (const float*)d_in[12];
  const float* r_b2 = (const float*)d_in[13];
  const float* rr_w = (const float*)d_in[14];
  const float* rr_b = (const float*)d_in[15];
  const float* e_w1 = (const float*)d_in[16];
  const float* e_b1 = (const float*)d_in[17];
  const float* e_w2 = (const float*)d_in[18];
  const float* e_b2 = (const float*)d_in[19];
  const float* alpha = (const float*)d_in[20];

  float* out = (float*)d_out;
  float* next  = out;
  float* stage = out + 8388608;
  float* gates = out + 16777216;
  float* slog  = out + 16842752;
  float* gw    = out + 16908288;
  float* rule  = out + 16941056;

  // router_input (8192x1280 f32 = 40MB) lives in the next+stage output
  // regions (64MB), which are only written by the final kernel.
  float* ri = out;

  char* ws = (char*)d_ws;
  float* mid = (float*)(ws);                    //  8 MB: gelu(bank@fp_w1+b1)
  float* r1  = (float*)(ws + 8388608);          //  8 MB: gelu(ri@r_w1+b1)
  u16* hnb   = (u16*)(ws + 16777216);           // 16 MB: h_norm bf16
  u16* w1t   = (u16*)(ws + 33554432);           //  4 MB: e_w1 B^T bf16
  u16* w2t   = (u16*)(ws + 37748736);           //  4 MB: e_w2 B^T bf16
  u16* apr   = (u16*)(ws + 41943040);           // 32 MB: gate*gelu(h1) bf16

  prep_kernel<<<16384, 256, 0, stream>>>(e_w1, e_w2, w1t, w2t);
  ln_kernel<<<NTOK, 256, 0, stream>>>(hidden, ln_g, ln_b, feat, rr_w, rr_b, ri, hnb, rule);
  sgemm_kernel<<<dim3(4, 128), 256, 0, stream>>>(feat_bank, 512, fp_w1, fp_b1, mid, 256, 512, 1);
  sgemm_kernel<<<dim3(4, 128), 256, 0, stream>>>(mid, 256, fp_w2, fp_b2, ri + 1024, 1280, 256, 0);
  sgemm_kernel<<<dim3(4, 128), 256, 0, stream>>>(ri, 1280, r_w1, r_b1, r1, 256, 1280, 1);
  gate_kernel<<<256, 256, 0, stream>>>(r1, r_w2, r_b2, gates, slog, gw);
  mfma_gemm<0><<<dim3(16, 64), 256, 0, stream>>>(hnb, w1t, 2048, 1024, e_b1, gates, apr,
                                                 nullptr, nullptr, nullptr, nullptr);
  mfma_gemm<1><<<dim3(8, 64), 256, 0, stream>>>(apr, w2t, 1024, 2048, e_b2, gates, nullptr,
                                                hidden, alpha, stage, next);
}

// Round 2
// 409.627 us; speedup vs baseline: 1.1513x; 1.1513x over previous
//
#include <hip/hip_runtime.h>
#include <stdint.h>

// ---------------------------------------------------------------------------
// StageBranchRunnerN2 round 1:
//  - router/proj chain: split-bf16 3-product MFMA GEMMs (hi/lo decomposition,
//    ~2^-18 effective precision -> top-2 selection safe) with split-K to fill
//    256 CUs (N=256 would otherwise give only 128 blocks of 128x128 tiles).
//  - all MFMA GEMMs stage via __builtin_amdgcn_global_load_lds width=16
//    (m97 pattern: barrier / GLL / barrier / ds_read+MFMA).
//  - scratch: ws = apr(32M) h_hi(16M) h_lo(16M) w2t(4M) = 68 MB (<= proven
//    75.5 MB); other temporaries live in the dead next/stage output regions
//    with liveness-ordered overwrites.
// ---------------------------------------------------------------------------

typedef unsigned short u16;
using bf16x8 = __attribute__((ext_vector_type(8))) short;
using f32x4  = __attribute__((ext_vector_type(4))) float;

__device__ __forceinline__ float gelu_tanh(float x) {
  float x3 = x * x * x;
  float t = tanhf(0.7978845608028654f * (x + 0.044715f * x3));
  return 0.5f * x * (1.0f + t);
}

__device__ __forceinline__ u16 f2bf(float f) {
  uint32_t u = __float_as_uint(f);
  u = u + 0x7fffu + ((u >> 16) & 1u);   // RNE
  return (u16)(u >> 16);
}
__device__ __forceinline__ float b2f(u16 h) {
  return __uint_as_float(((uint32_t)h) << 16);
}

__device__ __forceinline__ void gll16(const void* g, void* l) {
  __builtin_amdgcn_global_load_lds(
      (const __attribute__((address_space(1))) void*)g,
      (__attribute__((address_space(3))) void*)l, 16, 0, 0);
}

// ---------------------------------------------------------------------------
// split feat_bank (f32, 4M elems) -> hi/lo bf16
// ---------------------------------------------------------------------------
__global__ __launch_bounds__(256) void split_bank_kernel(const float* __restrict__ x,
    u16* __restrict__ hi, u16* __restrict__ lo) {
  int i4 = blockIdx.x * 256 + threadIdx.x;       // over 1M float4
  float4 v = ((const float4*)x)[i4];
  ushort4 h, l;
  h.x = f2bf(v.x); l.x = f2bf(v.x - b2f(h.x));
  h.y = f2bf(v.y); l.y = f2bf(v.y - b2f(h.y));
  h.z = f2bf(v.z); l.z = f2bf(v.z - b2f(h.z));
  h.w = f2bf(v.w); l.w = f2bf(v.w - b2f(h.w));
  ((ushort4*)hi)[i4] = h;
  ((ushort4*)lo)[i4] = l;
}

// ---------------------------------------------------------------------------
// weight prep: fp_w1 (512x256)->Bt hi/lo [256][512]; fp_w2 (256x256)->[256][256];
// r_w1 (1280x256)->[256][1280]; e_w2 (8,256,1024)->w2t[d][q] bf16 [1024][2048]
// ---------------------------------------------------------------------------
__global__ __launch_bounds__(256) void prep_w_kernel(
    const float* __restrict__ fp_w1, const float* __restrict__ fp_w2,
    const float* __restrict__ r_w1, const float* __restrict__ e_w2,
    u16* __restrict__ w1h, u16* __restrict__ w1l,
    u16* __restrict__ w2h, u16* __restrict__ w2l,
    u16* __restrict__ rwh, u16* __restrict__ rwl,
    u16* __restrict__ ew2t) {
  int idx = blockIdx.x * 256 + threadIdx.x;      // 2,621,440 total
  if (idx < 131072) {
    int n = idx >> 9, k = idx & 511;
    float v = fp_w1[k * 256 + n];
    u16 h = f2bf(v); w1h[idx] = h; w1l[idx] = f2bf(v - b2f(h));
  } else if (idx < 196608) {
    int j = idx - 131072;
    int n = j >> 8, k = j & 255;
    float v = fp_w2[k * 256 + n];
    u16 h = f2bf(v); w2h[j] = h; w2l[j] = f2bf(v - b2f(h));
  } else if (idx < 524288) {
    int j = idx - 196608;
    int n = j / 1280, k = j - n * 1280;
    float v = r_w1[k * 256 + n];
    u16 h = f2bf(v); rwh[j] = h; rwl[j] = f2bf(v - b2f(h));
  } else {
    int j = idx - 524288;                        // 2M: e_w2 transpose
    int d = j >> 11, q = j & 2047;
    ew2t[j] = f2bf(e_w2[q * 1024 + d]);
  }
}

// e_w1 (8,1024,256) -> w1t[n=e*256+h][k] bf16 (2048x1024 B^T)  [launched late:
// writes into the dead bank region of d_out]
__global__ __launch_bounds__(256) void prep_w1t_kernel(const float* __restrict__ ew1,
                                                       u16* __restrict__ w1t) {
  int idx = blockIdx.x * 256 + threadIdx.x;      // 2M
  int k = idx & 1023, n = idx >> 10;
  int e = n >> 8, h = n & 255;
  w1t[idx] = f2bf(ew1[(e << 18) + (k << 8) + h]);
}

// ---------------------------------------------------------------------------
// LayerNorm -> h_hi/h_lo bf16 split; also rule logits. One block per token.
// ---------------------------------------------------------------------------
__global__ __launch_bounds__(256) void ln_kernel(const float* __restrict__ hidden,
    const float* __restrict__ ln_g, const float* __restrict__ ln_b,
    const float* __restrict__ feat, const float* __restrict__ rr_w,
    const float* __restrict__ rr_b,
    u16* __restrict__ h_hi, u16* __restrict__ h_lo, float* __restrict__ rule) {
  int t = blockIdx.x;
  int tid = threadIdx.x;
  float4 v = ((const float4*)(hidden + (size_t)t * 1024))[tid];
  float s = v.x + v.y + v.z + v.w;
#pragma unroll
  for (int o = 32; o > 0; o >>= 1) s += __shfl_down(s, o);
  __shared__ float red[4];
  __shared__ float stats[2];
  int wid = tid >> 6, lane = tid & 63;
  if (lane == 0) red[wid] = s;
  __syncthreads();
  if (tid == 0) stats[0] = (red[0] + red[1] + red[2] + red[3]) * (1.0f / 1024.0f);
  __syncthreads();
  float mu = stats[0];
  float dx = v.x - mu, dy = v.y - mu, dz = v.z - mu, dw = v.w - mu;
  float q = dx * dx + dy * dy + dz * dz + dw * dw;
#pragma unroll
  for (int o = 32; o > 0; o >>= 1) q += __shfl_down(q, o);
  if (lane == 0) red[wid] = q;
  __syncthreads();
  if (tid == 0) {
    float var = (red[0] + red[1] + red[2] + red[3]) * (1.0f / 1024.0f) + 1e-5f;
    float r = rsqrtf(var);
    r = r * (1.5f - 0.5f * var * r * r);
    stats[1] = r;
  }
  __syncthreads();
  float r = stats[1];
  float4 g = ((const float4*)ln_g)[tid];
  float4 b = ((const float4*)ln_b)[tid];
  float4 o;
  o.x = dx * r * g.x + b.x;
  o.y = dy * r * g.y + b.y;
  o.z = dz * r * g.z + b.z;
  o.w = dw * r * g.w + b.w;
  ushort4 hv, lv;
  hv.x = f2bf(o.x); lv.x = f2bf(o.x - b2f(hv.x));
  hv.y = f2bf(o.y); lv.y = f2bf(o.y - b2f(hv.y));
  hv.z = f2bf(o.z); lv.z = f2bf(o.z - b2f(hv.z));
  hv.w = f2bf(o.w); lv.w = f2bf(o.w - b2f(hv.w));
  ((ushort4*)(h_hi + (size_t)t * 1024))[tid] = hv;
  ((ushort4*)(h_lo + (size_t)t * 1024))[tid] = lv;
  if (tid < 8) {
    float acc = rr_b[tid];
#pragma unroll
    for (int f = 0; f < 16; f++) acc += feat[t * 16 + f] * rr_w[f * 8 + tid];
    rule[t * 8 + tid] = acc;
  }
}

// ---------------------------------------------------------------------------
// split-bf16 3-product MFMA GEMM with split-K.
// C_partial[z] = A[:, kslice_z] @ B[kslice_z, :]   (A,B given as hi/lo bf16)
// A region routing: blocks z < nz1 use (Ah,Al,lda), k-offset z*kchunk;
// blocks z >= nz1 use (A2h,A2l,lda2), B k-offset bkoff2, length klen2.
// Tile 128x128 (N=256 -> gridDim.x=2), 16x16x32 MFMA, GLL staging.
// ---------------------------------------------------------------------------
__global__ __launch_bounds__(256) void gemm3_kernel(
    const u16* __restrict__ Ah, const u16* __restrict__ Al, int lda,
    int kchunk, int nz1,
    const u16* __restrict__ A2h, const u16* __restrict__ A2l, int lda2,
    int klen2, int bkoff2,
    const u16* __restrict__ Bth, const u16* __restrict__ Btl, int Kb,
    float* __restrict__ parts) {
  __shared__ u16 Ash[128 * 32];
  __shared__ u16 Asl[128 * 32];
  __shared__ u16 Bsh[128 * 32];
  __shared__ u16 Bsl[128 * 32];
  int tid = threadIdx.x;
  int z = blockIdx.z;
  const u16 *pAh, *pAl;
  int lda_, akoff, bkoff, klen;
  if (z < nz1) {
    pAh = Ah; pAl = Al; lda_ = lda; akoff = z * kchunk; bkoff = akoff; klen = kchunk;
  } else {
    pAh = A2h; pAl = A2l; lda_ = lda2; akoff = 0; bkoff = bkoff2; klen = klen2;
  }
  int row0 = blockIdx.y * 128, col0 = blockIdx.x * 128;
  int wave = tid >> 6, lane = tid & 63;
  int wr = (wave >> 1) * 64, wc = (wave & 1) * 64;
  int l16 = lane & 15, qd = lane >> 4;
  f32x4 acc[4][4];
#pragma unroll
  for (int i = 0; i < 4; i++)
#pragma unroll
    for (int j = 0; j < 4; j++) acc[i][j] = 0.0f;

  int r0 = tid >> 2, kc = tid & 3;
  const u16* gAh0 = pAh + (size_t)(row0 + r0) * lda_ + akoff + kc * 8;
  const u16* gAh1 = gAh0 + (size_t)64 * lda_;
  const u16* gAl0 = pAl + (size_t)(row0 + r0) * lda_ + akoff + kc * 8;
  const u16* gAl1 = gAl0 + (size_t)64 * lda_;
  const u16* gBh0 = Bth + (size_t)(col0 + r0) * Kb + bkoff + kc * 8;
  const u16* gBh1 = gBh0 + (size_t)64 * Kb;
  const u16* gBl0 = Btl + (size_t)(col0 + r0) * Kb + bkoff + kc * 8;
  const u16* gBl1 = gBl0 + (size_t)64 * Kb;
  u16* dAh = Ash + tid * 8;
  u16* dAl = Asl + tid * 8;
  u16* dBh = Bsh + tid * 8;
  u16* dBl = Bsl + tid * 8;

  for (int k0 = 0; k0 < klen; k0 += 32) {
    __syncthreads();
    gll16(gAh0 + k0, dAh);
    gll16(gAh1 + k0, dAh + 2048);
    gll16(gAl0 + k0, dAl);
    gll16(gAl1 + k0, dAl + 2048);
    gll16(gBh0 + k0, dBh);
    gll16(gBh1 + k0, dBh + 2048);
    gll16(gBl0 + k0, dBl);
    gll16(gBl1 + k0, dBl + 2048);
    __syncthreads();
    bf16x8 afh[4], afl[4], bfh[4], bfl[4];
#pragma unroll
    for (int i = 0; i < 4; i++) {
      afh[i] = *((const bf16x8*)(Ash + (wr + i * 16 + l16) * 32 + qd * 8));
      afl[i] = *((const bf16x8*)(Asl + (wr + i * 16 + l16) * 32 + qd * 8));
      bfh[i] = *((const bf16x8*)(Bsh + (wc + i * 16 + l16) * 32 + qd * 8));
      bfl[i] = *((const bf16x8*)(Bsl + (wc + i * 16 + l16) * 32 + qd * 8));
    }
#pragma unroll
    for (int i = 0; i < 4; i++)
#pragma unroll
      for (int j = 0; j < 4; j++) {
        acc[i][j] = __builtin_amdgcn_mfma_f32_16x16x32_bf16(afh[i], bfh[j], acc[i][j], 0, 0, 0);
        acc[i][j] = __builtin_amdgcn_mfma_f32_16x16x32_bf16(afl[i], bfh[j], acc[i][j], 0, 0, 0);
        acc[i][j] = __builtin_amdgcn_mfma_f32_16x16x32_bf16(afh[i], bfl[j], acc[i][j], 0, 0, 0);
      }
  }

  float* pz = parts + (size_t)z * 2097152;
#pragma unroll
  for (int i = 0; i < 4; i++)
#pragma unroll
    for (int j = 0; j < 4; j++) {
      int cl = wc + j * 16 + l16;
#pragma unroll
      for (int rr = 0; rr < 4; rr++) {
        int rl = wr + i * 16 + qd * 4 + rr;
        pz[(size_t)(row0 + rl) * 256 + col0 + cl] = acc[i][j][rr];
      }
    }
}

// ---------------------------------------------------------------------------
// epilogues: sum nz partial slices + bias (+gelu), emit bf16 hi/lo or f32
// ---------------------------------------------------------------------------
__global__ __launch_bounds__(256) void epi_bf_kernel(const float* __restrict__ parts,
    int nz, const float* __restrict__ bias, int do_gelu,
    u16* __restrict__ hi, u16* __restrict__ lo) {
  int i4 = blockIdx.x * 256 + threadIdx.x;       // over 524288 float4
  float4 s = ((const float4*)parts)[i4];
  for (int zz = 1; zz < nz; zz++) {
    float4 p = ((const float4*)parts)[(size_t)zz * 524288 + i4];
    s.x += p.x; s.y += p.y; s.z += p.z; s.w += p.w;
  }
  float4 bv = ((const float4*)bias)[i4 & 63];
  s.x += bv.x; s.y += bv.y; s.z += bv.z; s.w += bv.w;
  if (do_gelu) {
    s.x = gelu_tanh(s.x); s.y = gelu_tanh(s.y);
    s.z = gelu_tanh(s.z); s.w = gelu_tanh(s.w);
  }
  ushort4 h, l;
  h.x = f2bf(s.x); l.x = f2bf(s.x - b2f(h.x));
  h.y = f2bf(s.y); l.y = f2bf(s.y - b2f(h.y));
  h.z = f2bf(s.z); l.z = f2bf(s.z - b2f(h.z));
  h.w = f2bf(s.w); l.w = f2bf(s.w - b2f(h.w));
  ((ushort4*)hi)[i4] = h;
  ((ushort4*)lo)[i4] = l;
}

__global__ __launch_bounds__(256) void epi_f32_kernel(const float* __restrict__ parts,
    int nz, const float* __restrict__ bias, float* __restrict__ out) {
  int i4 = blockIdx.x * 256 + threadIdx.x;
  float4 s = ((const float4*)parts)[i4];
  for (int zz = 1; zz < nz; zz++) {
    float4 p = ((const float4*)parts)[(size_t)zz * 524288 + i4];
    s.x += p.x; s.y += p.y; s.z += p.z; s.w += p.w;
  }
  float4 bv = ((const float4*)bias)[i4 & 63];
  s.x = gelu_tanh(s.x + bv.x);
  s.y = gelu_tanh(s.y + bv.y);
  s.z = gelu_tanh(s.z + bv.z);
  s.w = gelu_tanh(s.w + bv.w);
  ((float4*)out)[i4] = s;
}

// ---------------------------------------------------------------------------
// Router head: logits = r1 @ r_w2 + r_b2 (f32); top-2 masked softmax.
// ---------------------------------------------------------------------------
__global__ __launch_bounds__(256) void gate_kernel(const float* __restrict__ r1,
    const float* __restrict__ r_w2, const float* __restrict__ r_b2,
    float* __restrict__ gates, float* __restrict__ slog, float* __restrict__ gw) {
  __shared__ float w2s[2048];
  __shared__ float r1s[32][260];
  __shared__ float lg[32][8];
  int tid = threadIdx.x;
  int t0 = blockIdx.x * 32;
  for (int i = tid; i < 2048; i += 256) w2s[i] = r_w2[i];
  for (int i = tid; i < 32 * 256; i += 256) {
    int tt = i >> 8, k = i & 255;
    r1s[tt][k] = r1[(size_t)(t0 + tt) * 256 + k];
  }
  __syncthreads();
  int tl = tid >> 3, e = tid & 7;
  float acc = r_b2[e];
  for (int k = 0; k < 256; k++) acc += r1s[tl][k] * w2s[k * 8 + e];
  lg[tl][e] = acc;
  __syncthreads();
  if (tid < 32) {
    int t = t0 + tid;
    float l[8];
#pragma unroll
    for (int i = 0; i < 8; i++) l[i] = lg[tid][i];
    float m1 = -1e30f, m2 = -1e30f;
#pragma unroll
    for (int i = 0; i < 8; i++) {
      float v = l[i];
      if (v > m1) { m2 = m1; m1 = v; }
      else if (v > m2) m2 = v;
    }
    float w[8];
    float se = 0.0f;
#pragma unroll
    for (int i = 0; i < 8; i++) {
      float ex = (l[i] >= m2) ? expf(l[i] - m1) : 0.0f;
      w[i] = ex;
      se += ex;
    }
    float inv = 1.0f / se;
#pragma unroll
    for (int i = 0; i < 8; i++) {
      gates[(size_t)t * 8 + i] = w[i] * inv;
      slog[(size_t)t * 8 + i] = l[i];
    }
#pragma unroll
    for (int gi = 0; gi < 4; gi++)
      gw[(size_t)t * 4 + gi] = (w[2 * gi] + w[2 * gi + 1]) * inv;
  }
}

// ---------------------------------------------------------------------------
// bf16 MFMA GEMM (expert path), GLL staging, 128x128 tile.
// MODE 0: +e_b1, gelu, *gate -> bf16 A' (N=2048)
// MODE 1: +sum_e g*e_b2, write stage_out & next_hidden (N=1024)
// ---------------------------------------------------------------------------
template <int MODE>
__global__ __launch_bounds__(256) void mfma_gemm(const u16* __restrict__ A,
    const u16* __restrict__ Bt, int N, int K,
    const float* __restrict__ bias, const float* __restrict__ gates,
    u16* __restrict__ outb, const float* __restrict__ hidden,
    const float* __restrict__ alpha_p, float* __restrict__ stage,
    float* __restrict__ next) {
  __shared__ u16 As[128 * 32];
  __shared__ u16 Bs[128 * 32];
  __shared__ float gs[128 * 8];
  __shared__ float b2s[8 * 128];
  int tid = threadIdx.x;
  int row0 = blockIdx.y * 128, col0 = blockIdx.x * 128;
  int wave = tid >> 6, lane = tid & 63;
  int wr = (wave >> 1) * 64, wc = (wave & 1) * 64;
  int l16 = lane & 15, qd = lane >> 4;
  f32x4 acc[4][4];
#pragma unroll
  for (int i = 0; i < 4; i++)
#pragma unroll
    for (int j = 0; j < 4; j++) acc[i][j] = 0.0f;

  int r0 = tid >> 2, kc = tid & 3;
  const u16* Ap0 = A + (size_t)(row0 + r0) * K + kc * 8;
  const u16* Ap1 = Ap0 + (size_t)64 * K;
  const u16* Bp0 = Bt + (size_t)(col0 + r0) * K + kc * 8;
  const u16* Bp1 = Bp0 + (size_t)64 * K;
  u16* dA = As + tid * 8;
  u16* dB = Bs + tid * 8;

  for (int k0 = 0; k0 < K; k0 += 32) {
    __syncthreads();
    gll16(Ap0 + k0, dA);
    gll16(Ap1 + k0, dA + 2048);
    gll16(Bp0 + k0, dB);
    gll16(Bp1 + k0, dB + 2048);
    __syncthreads();
    bf16x8 af[4], bfr[4];
#pragma unroll
    for (int i = 0; i < 4; i++) {
      af[i]  = *((const bf16x8*)(As + (wr + i * 16 + l16) * 32 + qd * 8));
      bfr[i] = *((const bf16x8*)(Bs + (wc + i * 16 + l16) * 32 + qd * 8));
    }
#pragma unroll
    for (int i = 0; i < 4; i++)
#pragma unroll
      for (int j = 0; j < 4; j++)
        acc[i][j] = __builtin_amdgcn_mfma_f32_16x16x32_bf16(af[i], bfr[j], acc[i][j], 0, 0, 0);
  }

  for (int i = tid; i < 1024; i += 256)
    gs[i] = gates[(size_t)(row0 + (i >> 3)) * 8 + (i & 7)];
  if (MODE == 1) {
    for (int i = tid; i < 1024; i += 256)
      b2s[i] = bias[(size_t)(i >> 7) * 1024 + col0 + (i & 127)];
  }
  __syncthreads();

  if (MODE == 0) {
#pragma unroll
    for (int i = 0; i < 4; i++) {
#pragma unroll
      for (int j = 0; j < 4; j++) {
        int cl = wc + j * 16 + l16;
        int col = col0 + cl;
        float bcol = bias[col];
        int e = col >> 8;
#pragma unroll
        for (int rr = 0; rr < 4; rr++) {
          int rl = wr + i * 16 + qd * 4 + rr;
          int row = row0 + rl;
          float v = acc[i][j][rr] + bcol;
          v = gelu_tanh(v) * gs[rl * 8 + e];
          outb[(size_t)row * N + col] = f2bf(v);
        }
      }
    }
  } else {
    float al = alpha_p[0];
#pragma unroll
    for (int i = 0; i < 4; i++) {
#pragma unroll
      for (int j = 0; j < 4; j++) {
        int cl = wc + j * 16 + l16;
        int col = col0 + cl;
#pragma unroll
        for (int rr = 0; rr < 4; rr++) {
          int rl = wr + i * 16 + qd * 4 + rr;
          int row = row0 + rl;
          float sb = 0.0f;
#pragma unroll
          for (int e = 0; e < 8; e++) sb += gs[rl * 8 + e] * b2s[e * 128 + cl];
          float v = acc[i][j][rr] + sb;
          size_t o = (size_t)row * N + col;
          stage[o] = v;
          next[o] = hidden[o] + al * v;
        }
      }
    }
  }
}

// ---------------------------------------------------------------------------
extern "C" void kernel_launch(void* const* d_in, const int* in_sizes, int n_in,
                              void* d_out, int out_size, void* d_ws, size_t ws_size,
                              hipStream_t stream) {
  const float* hidden    = (const float*)d_in[0];
  const float* feat      = (const float*)d_in[1];
  const float* feat_bank = (const float*)d_in[2];
  const float* ln_g  = (const float*)d_in[4];
  const float* ln_b  = (const float*)d_in[5];
  const float* fp_w1 = (const float*)d_in[6];
  const float* fp_b1 = (const float*)d_in[7];
  const float* fp_w2 = (const float*)d_in[8];
  const float* fp_b2 = (const float*)d_in[9];
  const float* r_w1  = (const float*)d_in[10];
  const float* r_b1  = (const float*)d_in[11];
  const float* r_w2  = (const float*)d_in[12];
  const float* r_b2  = (const float*)d_in[13];
  const float* rr_w  = (const float*)d_in[14];
  const float* rr_b  = (const float*)d_in[15];
  const float* e_w1  = (const float*)d_in[16];
  const float* e_b1  = (const float*)d_in[17];
  const float* e_w2  = (const float*)d_in[18];
  const float* e_b2  = (const float*)d_in[19];
  const float* alpha = (const float*)d_in[20];

  char* ob = (char*)d_out;
  // final outputs
  float* next  = (float*)ob;                         // 8192x1024
  float* stage = (float*)(ob + 33554432);            // 8192x1024
  float* gates = (float*)(ob + 67108864);            // 8192x8
  float* slog  = gates + 65536;
  float* gw    = slog + 65536;                       // 8192x4
  float* rule  = gw + 32768;                         // 8192x8

  // scratch in the (dead-until-last-kernel) next region
  u16* bank_hi  = (u16*)(ob);                        // 8 MB   [dies after proj1]
  u16* bank_lo  = (u16*)(ob + 8388608);              // 8 MB
  u16* fpw1t_hi = (u16*)(ob + 16777216);             // 256 KB [dies after proj1]
  u16* fpw1t_lo = (u16*)(ob + 17039360);             // 256 KB
  u16* mid_hi   = (u16*)(ob + 16777216);             // 4 MB   [written after fpw1t dead]
  u16* mid_lo   = (u16*)(ob + 20971520);             // 4 MB
  u16* fpw2t_hi = (u16*)(ob + 25165824);             // 128 KB [dies after proj2]
  u16* fpw2t_lo = (u16*)(ob + 25296896);             // 128 KB
  u16* proj_hi  = (u16*)(ob + 25165824);             // 4 MB   [written after fpw2t dead]
  u16* proj_lo  = (u16*)(ob + 29360128);             // 4 MB
  u16* w1t      = (u16*)(ob);                        // 4 MB   [written after bank dead]
  // scratch in the stage region
  char* sb = ob + 33554432;
  float* parts  = (float*)sb;                        // up to 3 x 8 MB
  u16* rw1t_hi  = (u16*)(sb + 25165824);             // 640 KB [dies after router gemm]
  u16* rw1t_lo  = (u16*)(sb + 25821184);             // 640 KB
  float* r1     = (float*)(sb + 25165824);           // 8 MB   [written after rw1t dead]

  char* ws = (char*)d_ws;
  u16* apr  = (u16*)ws;                              // 32 MB
  u16* h_hi = (u16*)(ws + 33554432);                 // 16 MB
  u16* h_lo = (u16*)(ws + 50331648);                 // 16 MB
  u16* w2t  = (u16*)(ws + 67108864);                 //  4 MB  (total 68 MB)

  split_bank_kernel<<<4096, 256, 0, stream>>>(feat_bank, bank_hi, bank_lo);
  prep_w_kernel<<<10240, 256, 0, stream>>>(fp_w1, fp_w2, r_w1, e_w2,
      fpw1t_hi, fpw1t_lo, fpw2t_hi, fpw2t_lo, rw1t_hi, rw1t_lo, w2t);
  ln_kernel<<<8192, 256, 0, stream>>>(hidden, ln_g, ln_b, feat, rr_w, rr_b,
                                      h_hi, h_lo, rule);
  // proj1: gelu(bank @ fp_w1 + b1), K=512, split-K=2
  gemm3_kernel<<<dim3(2, 64, 2), 256, 0, stream>>>(
      bank_hi, bank_lo, 512, 256, 2,
      bank_hi, bank_lo, 512, 0, 0,
      fpw1t_hi, fpw1t_lo, 512, parts);
  epi_bf_kernel<<<2048, 256, 0, stream>>>(parts, 2, fp_b1, 1, mid_hi, mid_lo);
  prep_w1t_kernel<<<8192, 256, 0, stream>>>(e_w1, w1t);
  // proj2: mid @ fp_w2 + b2, K=256, split-K=2
  gemm3_kernel<<<dim3(2, 64, 2), 256, 0, stream>>>(
      mid_hi, mid_lo, 256, 128, 2,
      mid_hi, mid_lo, 256, 0, 0,
      fpw2t_hi, fpw2t_lo, 256, parts);
  epi_bf_kernel<<<2048, 256, 0, stream>>>(parts, 2, fp_b2, 0, proj_hi, proj_lo);
  // router1: gelu([h_norm, proj] @ r_w1 + b1), K=1280 = 512(h)+512(h)+256(proj)
  gemm3_kernel<<<dim3(2, 64, 3), 256, 0, stream>>>(
      h_hi, h_lo, 1024, 512, 2,
      proj_hi, proj_lo, 256, 256, 1024,
      rw1t_hi, rw1t_lo, 1280, parts);
  epi_f32_kernel<<<2048, 256, 0, stream>>>(parts, 3, r_b1, r1);
  gate_kernel<<<256, 256, 0, stream>>>(r1, r_w2, r_b2, gates, slog, gw);
  mfma_gemm<0><<<dim3(16, 64), 256, 0, stream>>>(h_hi, w1t, 2048, 1024, e_b1, gates,
      apr, nullptr, nullptr, nullptr, nullptr);
  mfma_gemm<1><<<dim3(8, 64), 256, 0, stream>>>(apr, w2t, 1024, 2048, e_b2, gates,
      nullptr, hidden, alpha, stage, next);
}